// Round 10
// baseline (175.966 us; speedup 1.0000x reference)
//
#include <hip/hip_runtime.h>

#define NN 50000      // N_ENT
#define NR 100        // N_REL2
#define NB 16         // N_BASES
#define D  64         // DIM
#define NE 100000     // N_EDGES

#define HB  196       // histogram/scatter blocks
#define EPB 512       // edges per block in hist/scatter
#define ZB  196       // zero blocks (50176 node slots)
#define GB  ((NN * 16 + 255) / 256)   // gather blocks = 3125

#define CHUNK 128     // edges per edge block (4 waves x 2 groups x 16)
#define GROUPS 2
#define EGRID 1024    // >= sum ceil(len_r/128) <= 782+100

#define NPB 128       // nodes per node block (4 waves x 32)
#define NGRID ((NN + NPB - 1) / NPB)

typedef float f32x4  __attribute__((ext_vector_type(4)));
typedef short bf16x8 __attribute__((ext_vector_type(8)));   // 8 bf16 = 4 VGPRs

__device__ __forceinline__ short f2bf(float f) {            // fp32 -> bf16 RNE
    unsigned u = __float_as_uint(f);
    return (short)((u + 0x7FFFu + ((u >> 16) & 1u)) >> 16);
}

__device__ __forceinline__ bf16x8 pack8(f32x4 a, f32x4 b) {
    bf16x8 t;
    t[0] = f2bf(a.x); t[1] = f2bf(a.y); t[2] = f2bf(a.z); t[3] = f2bf(a.w);
    t[4] = f2bf(b.x); t[5] = f2bf(b.y); t[6] = f2bf(b.z); t[7] = f2bf(b.w);
    return t;
}

// K1: blocks [0,202) weight prep (transposed); [202,398) zero deg/nodeCur;
// [398,398+GB) x0 gather. All independent; zeroing completes before K2's atomics.
__global__ __launch_bounds__(256) void prep_all(
    const float* __restrict__ att1, const float* __restrict__ basis1,
    const float* __restrict__ root1,
    const float* __restrict__ att2, const float* __restrict__ basis2,
    const float* __restrict__ root2,
    const int* __restrict__ entity, const f32x4* __restrict__ emb4,
    float* __restrict__ Wt1, float* __restrict__ Wt2,
    float* __restrict__ rT1, float* __restrict__ rT2,
    f32x4* __restrict__ x04, int* __restrict__ deg, int* __restrict__ nodeCur)
{
    __shared__ float t[64 * 65];
    int b = blockIdx.x;
    if (b < 2 * NR) {
        int layer = b >= NR;
        int r = layer ? b - NR : b;
        const float* att   = layer ? att2 : att1;
        const float* basis = layer ? basis2 : basis1;
        float*       Wt    = layer ? Wt2 : Wt1;
        float a[NB];
#pragma unroll
        for (int bb = 0; bb < NB; ++bb) a[bb] = att[r * NB + bb];
#pragma unroll
        for (int i = 0; i < 16; ++i) {
            int idx = i * 256 + threadIdx.x;        // [k][d] linear
            float acc = 0.f;
#pragma unroll
            for (int bb = 0; bb < NB; ++bb) acc += a[bb] * basis[bb * 4096 + idx];
            t[(idx >> 6) * 65 + (idx & 63)] = acc;  // t[k][d], padded
        }
        __syncthreads();
#pragma unroll
        for (int i = 0; i < 16; ++i) {
            int j = i * 256 + threadIdx.x;          // [d][k] linear
            Wt[(size_t)r * 4096 + j] = t[(j & 63) * 65 + (j >> 6)];
        }
    } else if (b < 2 * NR + 2) {
        const float* root = (b == 2 * NR) ? root1 : root2;
        float*       rT   = (b == 2 * NR) ? rT1 : rT2;
#pragma unroll
        for (int i = 0; i < 16; ++i) {
            int idx = i * 256 + threadIdx.x;
            t[(idx >> 6) * 65 + (idx & 63)] = root[idx];
        }
        __syncthreads();
#pragma unroll
        for (int i = 0; i < 16; ++i) {
            int j = i * 256 + threadIdx.x;
            rT[j] = t[(j & 63) * 65 + (j >> 6)];
        }
    } else if (b < 2 * NR + 2 + ZB) {
        int i = (b - (2 * NR + 2)) * 256 + threadIdx.x;   // 0..50175
        deg[i] = 0; nodeCur[i] = 0;
    } else {
        int idx = (b - (2 * NR + 2 + ZB)) * 256 + threadIdx.x;  // over NN*16
        if (idx < NN * 16) {
            int n = idx >> 4;
            int q = idx & 15;
            x04[idx] = emb4[(size_t)entity[n] * 16 + q];
        }
    }
}

// K2: per-block relation histogram (LDS atomics) + node in-degree (int)
__global__ __launch_bounds__(256) void hist_edges(
    const int* __restrict__ et, const int* __restrict__ dst,
    int* __restrict__ blockHist, int* __restrict__ deg)
{
    __shared__ int lh[NR];
    for (int i = threadIdx.x; i < NR; i += 256) lh[i] = 0;
    __syncthreads();
#pragma unroll
    for (int i = 0; i < EPB / 256; ++i) {
        int e = blockIdx.x * EPB + i * 256 + threadIdx.x;
        if (e < NE) {
            atomicAdd(&lh[et[e]], 1);
            atomicAdd(&deg[dst[e]], 1);
        }
    }
    __syncthreads();
    for (int i = threadIdx.x; i < NR; i += 256)
        blockHist[blockIdx.x * NR + i] = lh[i];
}

// K3: blocks [0,NR) relation column scan; [NR,NR+ZB) node-degree block scan.
__global__ __launch_bounds__(256) void scans(
    const int* __restrict__ blockHist, int* __restrict__ blockPrefix,
    int* __restrict__ relTot, const int* __restrict__ deg,
    int* __restrict__ nodePre, int* __restrict__ blockSumN)
{
    __shared__ int sc[256];
    int t = threadIdx.x;
    if (blockIdx.x < NR) {
        int r = blockIdx.x;
        int v = (t < HB) ? blockHist[t * NR + r] : 0;
        sc[t] = v;
        __syncthreads();
#pragma unroll
        for (int off = 1; off < 256; off <<= 1) {
            int a = (t >= off) ? sc[t - off] : 0;
            __syncthreads();
            sc[t] += a;
            __syncthreads();
        }
        if (t < HB) blockPrefix[t * NR + r] = sc[t] - v;   // exclusive
        if (t == 0) relTot[r] = sc[255];
    } else {
        int b = blockIdx.x - NR;                  // 0..ZB-1
        int n = b * 256 + t;
        int v = deg[n];                            // zero-padded to 50176
        sc[t] = v;
        __syncthreads();
#pragma unroll
        for (int off = 1; off < 256; off <<= 1) {
            int a = (t >= off) ? sc[t - off] : 0;
            __syncthreads();
            sc[t] += a;
            __syncthreads();
        }
        nodePre[n] = sc[t] - v;                    // exclusive within block
        if (t == 255) blockSumN[b] = sc[255];
    }
}

// K4: relation offsets + chunk table + node block-base scan.
__global__ __launch_bounds__(256) void scanK(
    const int* __restrict__ relTot, const int* __restrict__ blockSumN,
    int* __restrict__ offs, int* __restrict__ nbG,
    int* __restrict__ tabR, int* __restrict__ tabS,
    int* __restrict__ nodeBlockBase)
{
    __shared__ int totL[NR];
    __shared__ int offL[NR + 1];
    __shared__ int cnbL[NR + 1];
    __shared__ int sc2[256];
    int t = threadIdx.x;
    if (t < NR) totL[t] = relTot[t];
    int v2 = (t < ZB) ? blockSumN[t] : 0;
    sc2[t] = v2;
    __syncthreads();
    if (t == 0) {
        int off = 0, cb = 0;
        for (int r = 0; r < NR; ++r) {
            offL[r] = off; cnbL[r] = cb;
            off += totL[r];
            cb  += (totL[r] + CHUNK - 1) / CHUNK;
        }
        offL[NR] = off; cnbL[NR] = cb;
    }
    __syncthreads();
#pragma unroll
    for (int off = 1; off < 256; off <<= 1) {
        int a = (t >= off) ? sc2[t - off] : 0;
        __syncthreads();
        sc2[t] += a;
        __syncthreads();
    }
    if (t < ZB) nodeBlockBase[t] = sc2[t] - v2;    // exclusive
    if (t == 0) nodeBlockBase[ZB] = sc2[255];      // = NE
    if (t <= NR) offs[t] = offL[t];
    if (t == 0) nbG[0] = cnbL[NR];
    int nb = cnbL[NR];
    for (int e = t; e < nb; e += 256) {
        int lo = 0, hi = NR;
        while (hi - lo > 1) { int mid = (lo + hi) >> 1; if (cnbL[mid] <= e) lo = mid; else hi = mid; }
        tabR[e] = lo;
        tabS[e] = offL[lo] + (e - cnbL[lo]) * CHUNK;
    }
}

// K5: double scatter — relation-sorted (srcS/normS at rel-pos p) and
// dst-CSR (dstIdx[q] = p), one pass over original edges.
__global__ __launch_bounds__(256) void scatter2(
    const int* __restrict__ src, const int* __restrict__ dst,
    const int* __restrict__ et, const float* __restrict__ en,
    const int* __restrict__ offs, const int* __restrict__ blockPrefix,
    const int* __restrict__ nodePre, const int* __restrict__ nodeBlockBase,
    int* __restrict__ nodeCur, int* __restrict__ srcS,
    float* __restrict__ normS, int* __restrict__ dstIdx)
{
    __shared__ int lcur[NR];
    for (int i = threadIdx.x; i < NR; i += 256)
        lcur[i] = offs[i] + blockPrefix[blockIdx.x * NR + i];
    __syncthreads();
#pragma unroll
    for (int i = 0; i < EPB / 256; ++i) {
        int e = blockIdx.x * EPB + i * 256 + threadIdx.x;
        if (e < NE) {
            int r = et[e];
            int p = atomicAdd(&lcur[r], 1);
            srcS[p] = src[e]; normS[p] = en[e];
            int n = dst[e];
            int q = nodeBlockBase[n >> 8] + nodePre[n] + atomicAdd(&nodeCur[n], 1);
            dstIdx[q] = p;
        }
    }
}

// Edge kernel: identical MFMA structure to R9 but PLAIN STORES of msg rows at
// their rel-sorted position p — zero atomics (R9's ~21us wall was 6.4M f32
// atomicAdds per dispatch at ~300G atomics/s).
__global__ __launch_bounds__(256, 4) void edge_mfma(
    const int* __restrict__ srcS, const float* __restrict__ normS,
    const int* __restrict__ offs, const int* __restrict__ tabR,
    const int* __restrict__ tabS, const int* __restrict__ nbG,
    const float* __restrict__ x, const float* __restrict__ Wt,
    float* __restrict__ msg)
{
    __shared__ float LW[64 * 68];                  // LW[d][k], 17 KB
    int b = blockIdx.x;
    if (b >= nbG[0]) return;
    int r  = tabR[b];
    int cs = tabS[b];
    int tid = threadIdx.x;

    {
        const f32x4* __restrict__ Wg = (const f32x4*)(Wt + (size_t)r * 4096);
#pragma unroll
        for (int i = 0; i < 4; ++i) {
            int v = tid + i * 256;
            int d = v >> 4, k4 = v & 15;
            *(f32x4*)(LW + d * 68 + k4 * 4) = Wg[v];
        }
    }
    __syncthreads();

    int lane = tid & 63, wid = tid >> 6;
    int c15 = lane & 15, kg = lane >> 4;

    bf16x8 B[4][2];
#pragma unroll
    for (int nt = 0; nt < 4; ++nt)
#pragma unroll
        for (int ks = 0; ks < 2; ++ks) {
            const f32x4* p = (const f32x4*)(LW + (nt * 16 + c15) * 68 + ks * 32 + kg * 8);
            B[nt][ks] = pack8(p[0], p[1]);
        }

    int segE = offs[r + 1];
    int bend = cs + CHUNK < segE ? cs + CHUNK : segE;

#pragma unroll 1
    for (int g = 0; g < GROUPS; ++g) {
        int gs = cs + wid * (GROUPS * 16) + g * 16;
        if (gs >= bend) break;
        int ge = gs + 16 < bend ? gs + 16 : bend;

        int e  = gs + c15;                         // A row = c15
        int ec = e < ge ? e : ge - 1;
        float nrm = (e < ge) ? normS[ec] : 0.f;
        int   sn  = srcS[ec];

        const f32x4* xr  = (const f32x4*)(x + (size_t)sn * 64 + kg * 8);
        const f32x4* xr2 = (const f32x4*)(x + (size_t)sn * 64 + 32 + kg * 8);
        bf16x8 A0 = pack8(xr[0]  * nrm, xr[1]  * nrm);
        bf16x8 A1 = pack8(xr2[0] * nrm, xr2[1] * nrm);

        f32x4 z = {0.f, 0.f, 0.f, 0.f};
        f32x4 acc[4] = {z, z, z, z};
#pragma unroll
        for (int nt = 0; nt < 4; ++nt) {
            acc[nt] = __builtin_amdgcn_mfma_f32_16x16x32_bf16(A0, B[nt][0], acc[nt], 0, 0, 0);
            acc[nt] = __builtin_amdgcn_mfma_f32_16x16x32_bf16(A1, B[nt][1], acc[nt], 0, 0, 0);
        }
#pragma unroll
        for (int nt = 0; nt < 4; ++nt)
#pragma unroll
            for (int j = 0; j < 4; ++j) {
                int er = gs + kg * 4 + j;          // C row = kg*4 + j
                if (er < ge)
                    msg[(size_t)er * 64 + nt * 16 + c15] = acc[nt][j];
            }
    }
}

// Node kernel: fused CSR aggregation (lane=dim gather of msg rows, mean via
// segment length) + root MFMA + bias. Agg bounced through per-wave LDS
// (stride 68 to spread banks). In-place-safe: waves own disjoint row ranges
// and read their rows before writing them.
__global__ __launch_bounds__(256, 4) void node_mfma(
    const float* __restrict__ x, const float* __restrict__ msg,
    const int* __restrict__ dstIdx, const int* __restrict__ nodePre,
    const int* __restrict__ nodeBlockBase, const float* __restrict__ rT,
    const float* __restrict__ bias, float* __restrict__ out)
{
    __shared__ float LW[64 * 68];
    __shared__ float aggL[4][32][68];
    int tid = threadIdx.x;
    {
        const f32x4* __restrict__ Rg = (const f32x4*)rT;
#pragma unroll
        for (int i = 0; i < 4; ++i) {
            int v = tid + i * 256;
            int d = v >> 4, k4 = v & 15;
            *(f32x4*)(LW + d * 68 + k4 * 4) = Rg[v];
        }
    }
    __syncthreads();

    int lane = tid & 63, wid = tid >> 6;
    int c15 = lane & 15, kg = lane >> 4;

    bf16x8 B[4][2];
#pragma unroll
    for (int nt = 0; nt < 4; ++nt)
#pragma unroll
        for (int ks = 0; ks < 2; ++ks) {
            const f32x4* p = (const f32x4*)(LW + (nt * 16 + c15) * 68 + ks * 32 + kg * 8);
            B[nt][ks] = pack8(p[0], p[1]);
        }
    float bv[4];
#pragma unroll
    for (int nt = 0; nt < 4; ++nt) bv[nt] = bias[nt * 16 + c15];

    int wbase = blockIdx.x * NPB + wid * 32;
    if (wbase >= NN) return;

    // --- aggregation phase: lane = dim ---
#pragma unroll 1
    for (int ln = 0; ln < 32; ++ln) {
        int n = wbase + ln;
        if (n >= NN) break;
        int blk  = n >> 8;
        int base = nodeBlockBase[blk];
        int lo = base + nodePre[n];
        int hi = ((n & 255) == 255) ? nodeBlockBase[blk + 1] : base + nodePre[n + 1];
        float acc = 0.f;
        for (int q = lo; q < hi; ++q)
            acc += msg[(size_t)dstIdx[q] * 64 + lane];
        float c = (float)(hi - lo);
        c = c > 1.f ? c : 1.f;
        aggL[wid][ln][lane] = acc / c;
    }
    // same-wave LDS write->read: compiler-inserted lgkmcnt suffices, no barrier.

    // --- root MFMA + epilogue ---
#pragma unroll 1
    for (int g = 0; g < 2; ++g) {
        int gs = wbase + g * 16;
        if (gs >= NN) break;
        int ge = gs + 16 < NN ? gs + 16 : NN;

        int n  = gs + c15;
        int nc = n < ge ? n : ge - 1;
        const f32x4* xr  = (const f32x4*)(x + (size_t)nc * 64 + kg * 8);
        const f32x4* xr2 = (const f32x4*)(x + (size_t)nc * 64 + 32 + kg * 8);
        bf16x8 A0 = pack8(xr[0], xr[1]);
        bf16x8 A1 = pack8(xr2[0], xr2[1]);

        f32x4 z = {0.f, 0.f, 0.f, 0.f};
        f32x4 acc[4] = {z, z, z, z};
#pragma unroll
        for (int nt = 0; nt < 4; ++nt) {
            acc[nt] = __builtin_amdgcn_mfma_f32_16x16x32_bf16(A0, B[nt][0], acc[nt], 0, 0, 0);
            acc[nt] = __builtin_amdgcn_mfma_f32_16x16x32_bf16(A1, B[nt][1], acc[nt], 0, 0, 0);
        }
#pragma unroll
        for (int nt = 0; nt < 4; ++nt)
#pragma unroll
            for (int j = 0; j < 4; ++j) {
                int nr = gs + kg * 4 + j;
                if (nr < ge)
                    out[(size_t)nr * 64 + nt * 16 + c15] =
                        aggL[wid][g * 16 + kg * 4 + j][nt * 16 + c15] + acc[nt][j] + bv[nt];
            }
    }
}

extern "C" void kernel_launch(void* const* d_in, const int* in_sizes, int n_in,
                              void* d_out, int out_size, void* d_ws, size_t ws_size,
                              hipStream_t stream) {
    const int*   entity    = (const int*)d_in[0];
    const int*   edge_index= (const int*)d_in[1];    // [2, NE]
    const int*   edge_type = (const int*)d_in[2];
    const float* edge_norm = (const float*)d_in[3];
    const float* emb       = (const float*)d_in[4];
    const float* basis1    = (const float*)d_in[5];
    const float* att1      = (const float*)d_in[6];
    const float* root1     = (const float*)d_in[7];
    const float* bias1     = (const float*)d_in[8];
    const float* basis2    = (const float*)d_in[9];
    const float* att2      = (const float*)d_in[10];
    const float* root2     = (const float*)d_in[11];
    const float* bias2     = (const float*)d_in[12];

    const int* src = edge_index;
    const int* dst = edge_index + NE;

    // float arrays first (16B alignment), ints after
    float* ws    = (float*)d_ws;
    float* Wt1   = ws;                           // NR*4096
    float* Wt2   = Wt1 + (size_t)NR * 4096;      // NR*4096
    float* rT1   = Wt2 + (size_t)NR * 4096;      // 4096
    float* rT2   = rT1 + 4096;                   // 4096
    float* x0    = rT2 + 4096;                   // NN*D
    float* msg   = x0  + (size_t)NN * D;         // NE*D  (25.6 MB)
    float* normS = msg + (size_t)NE * D;         // NE
    int*   offs        = (int*)(normS + NE);     // NR+1 (+pad)
    int*   relTot      = offs + NR + 3;          // NR
    int*   nbG         = relTot + NR;            // 1 (+pad)
    int*   blockHist   = nbG + 3;                // HB*NR
    int*   blockPrefix = blockHist + HB * NR;    // HB*NR
    int*   tabR        = blockPrefix + HB * NR;  // EGRID
    int*   tabS        = tabR + EGRID;           // EGRID
    int*   srcS        = tabS + EGRID;           // NE
    int*   deg         = srcS + NE;              // ZB*256 = 50176
    int*   nodePre     = deg + ZB * 256;         // 50176
    int*   nodeCur     = nodePre + ZB * 256;     // 50176
    int*   blockSumN   = nodeCur + ZB * 256;     // ZB (+pad)
    int*   nodeBB      = blockSumN + ZB + 4;     // ZB+1 (+pad)
    int*   dstIdx      = nodeBB + ZB + 5;        // NE

    float* out = (float*)d_out;

    prep_all<<<2 * NR + 2 + ZB + GB, 256, 0, stream>>>(
        att1, basis1, root1, att2, basis2, root2,
        entity, (const f32x4*)emb, Wt1, Wt2, rT1, rT2,
        (f32x4*)x0, deg, nodeCur);
    hist_edges<<<HB, 256, 0, stream>>>(edge_type, dst, blockHist, deg);
    scans<<<NR + ZB, 256, 0, stream>>>(blockHist, blockPrefix, relTot,
                                       deg, nodePre, blockSumN);
    scanK<<<1, 256, 0, stream>>>(relTot, blockSumN, offs, nbG, tabR, tabS, nodeBB);
    scatter2<<<HB, 256, 0, stream>>>(src, dst, edge_type, edge_norm,
                                     offs, blockPrefix, nodePre, nodeBB,
                                     nodeCur, srcS, normS, dstIdx);

    // ---- layer 1 ----
    edge_mfma<<<EGRID, 256, 0, stream>>>(srcS, normS, offs, tabR, tabS, nbG,
                                         x0, Wt1, msg);
    node_mfma<<<NGRID, 256, 0, stream>>>(x0, msg, dstIdx, nodePre, nodeBB,
                                         rT1, bias1, out);

    // ---- layer 2 ----
    edge_mfma<<<EGRID, 256, 0, stream>>>(srcS, normS, offs, tabR, tabS, nbG,
                                         out, Wt2, msg);
    node_mfma<<<NGRID, 256, 0, stream>>>(out, msg, dstIdx, nodePre, nodeBB,
                                         rT2, bias2, out);
}

// Round 11
// 128.456 us; speedup vs baseline: 1.3699x; 1.3699x over previous
//
#include <hip/hip_runtime.h>

#define NN 50000      // N_ENT
#define NR 100        // N_REL2
#define NB 16         // N_BASES
#define D  64         // DIM
#define NE 100000     // N_EDGES

#define HB  196       // histogram/scatter blocks
#define EPB 512       // edges per block in hist/scatter
#define ZB  196       // zero blocks (50176 node slots)
#define GB  ((NN * 16 + 255) / 256)   // gather blocks = 3125

#define CHUNK 128     // edges per edge block (4 waves x 2 groups x 16)
#define GROUPS 2
#define EGRID 1024    // >= sum ceil(len_r/128) <= 782+100

#define NPB 128       // nodes per node block (4 waves x 2 groups x 16)
#define NGRID ((NN + NPB - 1) / NPB)

typedef float f32x4  __attribute__((ext_vector_type(4)));
typedef short bf16x8 __attribute__((ext_vector_type(8)));   // 8 bf16 = 4 VGPRs

__device__ __forceinline__ short f2bf(float f) {            // fp32 -> bf16 RNE
    unsigned u = __float_as_uint(f);
    return (short)((u + 0x7FFFu + ((u >> 16) & 1u)) >> 16);
}

__device__ __forceinline__ bf16x8 pack8(f32x4 a, f32x4 b) {
    bf16x8 t;
    t[0] = f2bf(a.x); t[1] = f2bf(a.y); t[2] = f2bf(a.z); t[3] = f2bf(a.w);
    t[4] = f2bf(b.x); t[5] = f2bf(b.y); t[6] = f2bf(b.z); t[7] = f2bf(b.w);
    return t;
}

// K1: blocks [0,202) weight prep (transposed); [202,398) zero deg/nodeCur;
// [398,398+GB) x0 gather.
__global__ __launch_bounds__(256) void prep_all(
    const float* __restrict__ att1, const float* __restrict__ basis1,
    const float* __restrict__ root1,
    const float* __restrict__ att2, const float* __restrict__ basis2,
    const float* __restrict__ root2,
    const int* __restrict__ entity, const f32x4* __restrict__ emb4,
    float* __restrict__ Wt1, float* __restrict__ Wt2,
    float* __restrict__ rT1, float* __restrict__ rT2,
    f32x4* __restrict__ x04, int* __restrict__ deg, int* __restrict__ nodeCur)
{
    __shared__ float t[64 * 65];
    int b = blockIdx.x;
    if (b < 2 * NR) {
        int layer = b >= NR;
        int r = layer ? b - NR : b;
        const float* att   = layer ? att2 : att1;
        const float* basis = layer ? basis2 : basis1;
        float*       Wt    = layer ? Wt2 : Wt1;
        float a[NB];
#pragma unroll
        for (int bb = 0; bb < NB; ++bb) a[bb] = att[r * NB + bb];
#pragma unroll
        for (int i = 0; i < 16; ++i) {
            int idx = i * 256 + threadIdx.x;        // [k][d] linear
            float acc = 0.f;
#pragma unroll
            for (int bb = 0; bb < NB; ++bb) acc += a[bb] * basis[bb * 4096 + idx];
            t[(idx >> 6) * 65 + (idx & 63)] = acc;  // t[k][d], padded
        }
        __syncthreads();
#pragma unroll
        for (int i = 0; i < 16; ++i) {
            int j = i * 256 + threadIdx.x;          // [d][k] linear
            Wt[(size_t)r * 4096 + j] = t[(j & 63) * 65 + (j >> 6)];
        }
    } else if (b < 2 * NR + 2) {
        const float* root = (b == 2 * NR) ? root1 : root2;
        float*       rT   = (b == 2 * NR) ? rT1 : rT2;
#pragma unroll
        for (int i = 0; i < 16; ++i) {
            int idx = i * 256 + threadIdx.x;
            t[(idx >> 6) * 65 + (idx & 63)] = root[idx];
        }
        __syncthreads();
#pragma unroll
        for (int i = 0; i < 16; ++i) {
            int j = i * 256 + threadIdx.x;
            rT[j] = t[(j & 63) * 65 + (j >> 6)];
        }
    } else if (b < 2 * NR + 2 + ZB) {
        int i = (b - (2 * NR + 2)) * 256 + threadIdx.x;   // 0..50175
        deg[i] = 0; nodeCur[i] = 0;
    } else {
        int idx = (b - (2 * NR + 2 + ZB)) * 256 + threadIdx.x;  // over NN*16
        if (idx < NN * 16) {
            int n = idx >> 4;
            int q = idx & 15;
            x04[idx] = emb4[(size_t)entity[n] * 16 + q];
        }
    }
}

// K2: per-block relation histogram (LDS atomics) + node in-degree (int)
__global__ __launch_bounds__(256) void hist_edges(
    const int* __restrict__ et, const int* __restrict__ dst,
    int* __restrict__ blockHist, int* __restrict__ deg)
{
    __shared__ int lh[NR];
    for (int i = threadIdx.x; i < NR; i += 256) lh[i] = 0;
    __syncthreads();
#pragma unroll
    for (int i = 0; i < EPB / 256; ++i) {
        int e = blockIdx.x * EPB + i * 256 + threadIdx.x;
        if (e < NE) {
            atomicAdd(&lh[et[e]], 1);
            atomicAdd(&deg[dst[e]], 1);
        }
    }
    __syncthreads();
    for (int i = threadIdx.x; i < NR; i += 256)
        blockHist[blockIdx.x * NR + i] = lh[i];
}

// K3: blocks [0,NR) relation column scan; [NR,NR+ZB) node-degree block scan.
__global__ __launch_bounds__(256) void scans(
    const int* __restrict__ blockHist, int* __restrict__ blockPrefix,
    int* __restrict__ relTot, const int* __restrict__ deg,
    int* __restrict__ nodePre, int* __restrict__ blockSumN)
{
    __shared__ int sc[256];
    int t = threadIdx.x;
    if (blockIdx.x < NR) {
        int r = blockIdx.x;
        int v = (t < HB) ? blockHist[t * NR + r] : 0;
        sc[t] = v;
        __syncthreads();
#pragma unroll
        for (int off = 1; off < 256; off <<= 1) {
            int a = (t >= off) ? sc[t - off] : 0;
            __syncthreads();
            sc[t] += a;
            __syncthreads();
        }
        if (t < HB) blockPrefix[t * NR + r] = sc[t] - v;   // exclusive
        if (t == 0) relTot[r] = sc[255];
    } else {
        int b = blockIdx.x - NR;                  // 0..ZB-1
        int n = b * 256 + t;
        int v = deg[n];                            // zero-padded to 50176
        sc[t] = v;
        __syncthreads();
#pragma unroll
        for (int off = 1; off < 256; off <<= 1) {
            int a = (t >= off) ? sc[t - off] : 0;
            __syncthreads();
            sc[t] += a;
            __syncthreads();
        }
        nodePre[n] = sc[t] - v;                    // exclusive within block
        if (t == 255) blockSumN[b] = sc[255];
    }
}

// K4: relation offsets + chunk table + node block-base scan.
__global__ __launch_bounds__(256) void scanK(
    const int* __restrict__ relTot, const int* __restrict__ blockSumN,
    int* __restrict__ offs, int* __restrict__ nbG,
    int* __restrict__ tabR, int* __restrict__ tabS,
    int* __restrict__ nodeBlockBase)
{
    __shared__ int totL[NR];
    __shared__ int offL[NR + 1];
    __shared__ int cnbL[NR + 1];
    __shared__ int sc2[256];
    int t = threadIdx.x;
    if (t < NR) totL[t] = relTot[t];
    int v2 = (t < ZB) ? blockSumN[t] : 0;
    sc2[t] = v2;
    __syncthreads();
    if (t == 0) {
        int off = 0, cb = 0;
        for (int r = 0; r < NR; ++r) {
            offL[r] = off; cnbL[r] = cb;
            off += totL[r];
            cb  += (totL[r] + CHUNK - 1) / CHUNK;
        }
        offL[NR] = off; cnbL[NR] = cb;
    }
    __syncthreads();
#pragma unroll
    for (int off = 1; off < 256; off <<= 1) {
        int a = (t >= off) ? sc2[t - off] : 0;
        __syncthreads();
        sc2[t] += a;
        __syncthreads();
    }
    if (t < ZB) nodeBlockBase[t] = sc2[t] - v2;    // exclusive
    if (t == 0) nodeBlockBase[ZB] = sc2[255];      // = NE
    if (t <= NR) offs[t] = offL[t];
    if (t == 0) nbG[0] = cnbL[NR];
    int nb = cnbL[NR];
    for (int e = t; e < nb; e += 256) {
        int lo = 0, hi = NR;
        while (hi - lo > 1) { int mid = (lo + hi) >> 1; if (cnbL[mid] <= e) lo = mid; else hi = mid; }
        tabR[e] = lo;
        tabS[e] = offL[lo] + (e - cnbL[lo]) * CHUNK;
    }
}

// K5: double scatter — relation-sorted (srcS/normS at rel-pos p) and
// dst-CSR (dstIdx[q] = p), one pass over original edges.
__global__ __launch_bounds__(256) void scatter2(
    const int* __restrict__ src, const int* __restrict__ dst,
    const int* __restrict__ et, const float* __restrict__ en,
    const int* __restrict__ offs, const int* __restrict__ blockPrefix,
    const int* __restrict__ nodePre, const int* __restrict__ nodeBlockBase,
    int* __restrict__ nodeCur, int* __restrict__ srcS,
    float* __restrict__ normS, int* __restrict__ dstIdx)
{
    __shared__ int lcur[NR];
    for (int i = threadIdx.x; i < NR; i += 256)
        lcur[i] = offs[i] + blockPrefix[blockIdx.x * NR + i];
    __syncthreads();
#pragma unroll
    for (int i = 0; i < EPB / 256; ++i) {
        int e = blockIdx.x * EPB + i * 256 + threadIdx.x;
        if (e < NE) {
            int r = et[e];
            int p = atomicAdd(&lcur[r], 1);
            srcS[p] = src[e]; normS[p] = en[e];
            int n = dst[e];
            int q = nodeBlockBase[n >> 8] + nodePre[n] + atomicAdd(&nodeCur[n], 1);
            dstIdx[q] = p;
        }
    }
}

// Edge kernel: MFMA + plain stores of msg rows at rel-sorted position.
__global__ __launch_bounds__(256, 4) void edge_mfma(
    const int* __restrict__ srcS, const float* __restrict__ normS,
    const int* __restrict__ offs, const int* __restrict__ tabR,
    const int* __restrict__ tabS, const int* __restrict__ nbG,
    const float* __restrict__ x, const float* __restrict__ Wt,
    float* __restrict__ msg)
{
    __shared__ float LW[64 * 68];                  // LW[d][k], 17 KB
    int b = blockIdx.x;
    if (b >= nbG[0]) return;
    int r  = tabR[b];
    int cs = tabS[b];
    int tid = threadIdx.x;

    {
        const f32x4* __restrict__ Wg = (const f32x4*)(Wt + (size_t)r * 4096);
#pragma unroll
        for (int i = 0; i < 4; ++i) {
            int v = tid + i * 256;
            int d = v >> 4, k4 = v & 15;
            *(f32x4*)(LW + d * 68 + k4 * 4) = Wg[v];
        }
    }
    __syncthreads();

    int lane = tid & 63, wid = tid >> 6;
    int c15 = lane & 15, kg = lane >> 4;

    bf16x8 B[4][2];
#pragma unroll
    for (int nt = 0; nt < 4; ++nt)
#pragma unroll
        for (int ks = 0; ks < 2; ++ks) {
            const f32x4* p = (const f32x4*)(LW + (nt * 16 + c15) * 68 + ks * 32 + kg * 8);
            B[nt][ks] = pack8(p[0], p[1]);
        }

    int segE = offs[r + 1];
    int bend = cs + CHUNK < segE ? cs + CHUNK : segE;

#pragma unroll 1
    for (int g = 0; g < GROUPS; ++g) {
        int gs = cs + wid * (GROUPS * 16) + g * 16;
        if (gs >= bend) break;
        int ge = gs + 16 < bend ? gs + 16 : bend;

        int e  = gs + c15;                         // A row = c15
        int ec = e < ge ? e : ge - 1;
        float nrm = (e < ge) ? normS[ec] : 0.f;
        int   sn  = srcS[ec];

        const f32x4* xr  = (const f32x4*)(x + (size_t)sn * 64 + kg * 8);
        const f32x4* xr2 = (const f32x4*)(x + (size_t)sn * 64 + 32 + kg * 8);
        bf16x8 A0 = pack8(xr[0]  * nrm, xr[1]  * nrm);
        bf16x8 A1 = pack8(xr2[0] * nrm, xr2[1] * nrm);

        f32x4 z = {0.f, 0.f, 0.f, 0.f};
        f32x4 acc[4] = {z, z, z, z};
#pragma unroll
        for (int nt = 0; nt < 4; ++nt) {
            acc[nt] = __builtin_amdgcn_mfma_f32_16x16x32_bf16(A0, B[nt][0], acc[nt], 0, 0, 0);
            acc[nt] = __builtin_amdgcn_mfma_f32_16x16x32_bf16(A1, B[nt][1], acc[nt], 0, 0, 0);
        }
#pragma unroll
        for (int nt = 0; nt < 4; ++nt)
#pragma unroll
            for (int j = 0; j < 4; ++j) {
                int er = gs + kg * 4 + j;          // C row = kg*4 + j
                if (er < ge)
                    msg[(size_t)er * 64 + nt * 16 + c15] = acc[nt][j];
            }
    }
}

// Aggregation kernel: one wave per node, lane = dim. No LDS -> full occupancy;
// gather latency hidden by 50k independent waves (R10's fused version ran at
// 1 block/CU with a serial 32-node chain: 58us, VALUBusy 7%).
__global__ __launch_bounds__(256) void agg_mean(
    const float* __restrict__ msg, const int* __restrict__ dstIdx,
    const int* __restrict__ nodePre, const int* __restrict__ nodeBB,
    float* __restrict__ agg)
{
    int n    = blockIdx.x * 4 + (threadIdx.x >> 6);
    int lane = threadIdx.x & 63;
    if (n >= NN) return;
    int blk  = n >> 8;
    int base = nodeBB[blk];
    int lo = base + nodePre[n];
    int hi = ((n & 255) == 255) ? nodeBB[blk + 1] : base + nodePre[n + 1];
    float acc = 0.f;
    for (int q = lo; q < hi; ++q)
        acc += msg[(size_t)dstIdx[q] * 64 + lane];
    float c = (float)(hi - lo);
    c = c > 1.f ? c : 1.f;
    agg[(size_t)n * 64 + lane] = acc / c;
}

// Node kernel (lean R9 shape): out = agg + x@root + bias. 17 KB LDS.
// In-place-safe: waves own disjoint rows, read before write.
__global__ __launch_bounds__(256, 4) void node_mfma(
    const float* __restrict__ x, const float* __restrict__ agg,
    const float* __restrict__ rT, const float* __restrict__ bias,
    float* __restrict__ out)
{
    __shared__ float LW[64 * 68];
    int tid = threadIdx.x;
    {
        const f32x4* __restrict__ Rg = (const f32x4*)rT;
#pragma unroll
        for (int i = 0; i < 4; ++i) {
            int v = tid + i * 256;
            int d = v >> 4, k4 = v & 15;
            *(f32x4*)(LW + d * 68 + k4 * 4) = Rg[v];
        }
    }
    __syncthreads();

    int lane = tid & 63, wid = tid >> 6;
    int c15 = lane & 15, kg = lane >> 4;

    bf16x8 B[4][2];
#pragma unroll
    for (int nt = 0; nt < 4; ++nt)
#pragma unroll
        for (int ks = 0; ks < 2; ++ks) {
            const f32x4* p = (const f32x4*)(LW + (nt * 16 + c15) * 68 + ks * 32 + kg * 8);
            B[nt][ks] = pack8(p[0], p[1]);
        }
    float bv[4];
#pragma unroll
    for (int nt = 0; nt < 4; ++nt) bv[nt] = bias[nt * 16 + c15];

#pragma unroll 1
    for (int g = 0; g < GROUPS; ++g) {
        int gs = blockIdx.x * NPB + wid * (GROUPS * 16) + g * 16;
        if (gs >= NN) break;
        int ge = gs + 16 < NN ? gs + 16 : NN;

        int n  = gs + c15;
        int nc = n < ge ? n : ge - 1;
        const f32x4* xr  = (const f32x4*)(x + (size_t)nc * 64 + kg * 8);
        const f32x4* xr2 = (const f32x4*)(x + (size_t)nc * 64 + 32 + kg * 8);
        bf16x8 A0 = pack8(xr[0], xr[1]);
        bf16x8 A1 = pack8(xr2[0], xr2[1]);

        f32x4 z = {0.f, 0.f, 0.f, 0.f};
        f32x4 acc[4] = {z, z, z, z};
#pragma unroll
        for (int nt = 0; nt < 4; ++nt) {
            acc[nt] = __builtin_amdgcn_mfma_f32_16x16x32_bf16(A0, B[nt][0], acc[nt], 0, 0, 0);
            acc[nt] = __builtin_amdgcn_mfma_f32_16x16x32_bf16(A1, B[nt][1], acc[nt], 0, 0, 0);
        }
#pragma unroll
        for (int nt = 0; nt < 4; ++nt)
#pragma unroll
            for (int j = 0; j < 4; ++j) {
                int nr = gs + kg * 4 + j;
                if (nr < ge) {
                    size_t off = (size_t)nr * 64 + nt * 16 + c15;
                    out[off] = agg[off] + acc[nt][j] + bv[nt];
                }
            }
    }
}

extern "C" void kernel_launch(void* const* d_in, const int* in_sizes, int n_in,
                              void* d_out, int out_size, void* d_ws, size_t ws_size,
                              hipStream_t stream) {
    const int*   entity    = (const int*)d_in[0];
    const int*   edge_index= (const int*)d_in[1];    // [2, NE]
    const int*   edge_type = (const int*)d_in[2];
    const float* edge_norm = (const float*)d_in[3];
    const float* emb       = (const float*)d_in[4];
    const float* basis1    = (const float*)d_in[5];
    const float* att1      = (const float*)d_in[6];
    const float* root1     = (const float*)d_in[7];
    const float* bias1     = (const float*)d_in[8];
    const float* basis2    = (const float*)d_in[9];
    const float* att2      = (const float*)d_in[10];
    const float* root2     = (const float*)d_in[11];
    const float* bias2     = (const float*)d_in[12];

    const int* src = edge_index;
    const int* dst = edge_index + NE;

    // float arrays first (16B alignment), ints after
    float* ws    = (float*)d_ws;
    float* Wt1   = ws;                           // NR*4096
    float* Wt2   = Wt1 + (size_t)NR * 4096;      // NR*4096
    float* rT1   = Wt2 + (size_t)NR * 4096;      // 4096
    float* rT2   = rT1 + 4096;                   // 4096
    float* x0    = rT2 + 4096;                   // NN*D
    float* msg   = x0  + (size_t)NN * D;         // NE*D  (25.6 MB)
    float* agg   = msg + (size_t)NE * D;         // NN*D  (12.8 MB)
    float* normS = agg + (size_t)NN * D;         // NE
    int*   offs        = (int*)(normS + NE);     // NR+1 (+pad)
    int*   relTot      = offs + NR + 3;          // NR
    int*   nbG         = relTot + NR;            // 1 (+pad)
    int*   blockHist   = nbG + 3;                // HB*NR
    int*   blockPrefix = blockHist + HB * NR;    // HB*NR
    int*   tabR        = blockPrefix + HB * NR;  // EGRID
    int*   tabS        = tabR + EGRID;           // EGRID
    int*   srcS        = tabS + EGRID;           // NE
    int*   deg         = srcS + NE;              // ZB*256 = 50176
    int*   nodePre     = deg + ZB * 256;         // 50176
    int*   nodeCur     = nodePre + ZB * 256;     // 50176
    int*   blockSumN   = nodeCur + ZB * 256;     // ZB (+pad)
    int*   nodeBB      = blockSumN + ZB + 4;     // ZB+1 (+pad)
    int*   dstIdx      = nodeBB + ZB + 5;        // NE

    float* out = (float*)d_out;

    prep_all<<<2 * NR + 2 + ZB + GB, 256, 0, stream>>>(
        att1, basis1, root1, att2, basis2, root2,
        entity, (const f32x4*)emb, Wt1, Wt2, rT1, rT2,
        (f32x4*)x0, deg, nodeCur);
    hist_edges<<<HB, 256, 0, stream>>>(edge_type, dst, blockHist, deg);
    scans<<<NR + ZB, 256, 0, stream>>>(blockHist, blockPrefix, relTot,
                                       deg, nodePre, blockSumN);
    scanK<<<1, 256, 0, stream>>>(relTot, blockSumN, offs, nbG, tabR, tabS, nodeBB);
    scatter2<<<HB, 256, 0, stream>>>(src, dst, edge_type, edge_norm,
                                     offs, blockPrefix, nodePre, nodeBB,
                                     nodeCur, srcS, normS, dstIdx);

    // ---- layer 1 ----
    edge_mfma<<<EGRID, 256, 0, stream>>>(srcS, normS, offs, tabR, tabS, nbG,
                                         x0, Wt1, msg);
    agg_mean<<<(NN + 3) / 4, 256, 0, stream>>>(msg, dstIdx, nodePre, nodeBB, agg);
    node_mfma<<<NGRID, 256, 0, stream>>>(x0, agg, rT1, bias1, out);

    // ---- layer 2 ----
    edge_mfma<<<EGRID, 256, 0, stream>>>(srcS, normS, offs, tabR, tabS, nbG,
                                         out, Wt2, msg);
    agg_mean<<<(NN + 3) / 4, 256, 0, stream>>>(msg, dstIdx, nodePre, nodeBB, agg);
    node_mfma<<<NGRID, 256, 0, stream>>>(out, agg, rT2, bias2, out);
}